// Round 7
// baseline (33.992 us; speedup 1.0000x reference)
//
#include <hip/hip_runtime.h>
#include <hip/hip_bf16.h>
#include <cstddef>

#define BB 2
#define HH 64
#define WW 64
#define SCALE 0.17677669529663687f   // 32^-0.5

// K2 tile geometry (round-5 proven): 4x8 queries, all 4 heads per block
#define HALO_H 10
#define HALO_W 14
#define NPIX 140
#define NQ 32

typedef short short8 __attribute__((ext_vector_type(8)));
typedef float f32x4 __attribute__((ext_vector_type(4)));

__device__ inline ushort f2bf(float f) {
    union { __hip_bfloat16 b; ushort u; } cv;
    cv.b = __float2bfloat16(f);
    return cv.u;
}
__device__ inline float bflo(uint u) { union { uint i; float f; } c; c.i = u << 16; return c.f; }
__device__ inline float bfhi(uint u) { union { uint i; float f; } c; c.i = u & 0xffff0000u; return c.f; }

// ---------------------------------------------------------------------------
// K0: weight transpose f32 -> bf16, LDS-tiled (coalesced on both sides).
// Blocks 0..5: w_qkv (128x384) -> Wt rows 0..383.
// Blocks 6..7: w_proj (128x128) -> Wt rows 384..511.  Wt[n][k], k=0..127.
// ---------------------------------------------------------------------------
__global__ __launch_bounds__(256) void cvt_w_kernel(
    const float* __restrict__ w_qkv, const float* __restrict__ w_proj,
    ushort* __restrict__ Wt)
{
    __shared__ float Ws[128 * 65];     // 64 cols + pad
    const int tid = threadIdx.x;
    const int blk = blockIdx.x;
    const float* src = (blk < 6) ? w_qkv : w_proj;
    const int srcN  = (blk < 6) ? 384 : 128;
    const int n0    = (blk < 6) ? blk * 64 : (blk - 6) * 64;
    const int obase = (blk < 6) ? n0 : 384 + n0;

    // read 128(k) x 64(n) f32, coalesced
    #pragma unroll
    for (int t = 0; t < 8; ++t) {
        int idx = tid + t * 256;               // 0..2047
        int k = idx >> 4, c4 = idx & 15;
        float4 v = *(const float4*)(src + (size_t)k * srcN + n0 + c4 * 4);
        Ws[k * 65 + c4 * 4 + 0] = v.x;
        Ws[k * 65 + c4 * 4 + 1] = v.y;
        Ws[k * 65 + c4 * 4 + 2] = v.z;
        Ws[k * 65 + c4 * 4 + 3] = v.w;
    }
    __syncthreads();

    // write Wt[n][k] as uint4 (8 bf16)
    const int n = tid & 63;
    #pragma unroll
    for (int t = 0; t < 4; ++t) {
        int c = (tid >> 6) + t * 4;            // k-chunk 0..15
        union { ushort s[8]; uint4 q; } u;
        #pragma unroll
        for (int e = 0; e < 8; ++e) u.s[e] = f2bf(Ws[(c * 8 + e) * 65 + n]);
        *(uint4*)&Wt[(size_t)(obase + n) * 128 + c * 8] = u.q;
    }
}

// ---------------------------------------------------------------------------
// K1: qkv = x @ w_qkv + b_qkv (q cols pre-scaled), bf16 out.
// BM=64 x BN=192, K=128 staged (XOR-swizzled chunks). 4 waves, 2x2 quadrants,
// 2x6 16x16x32 frags. Epilogue via LDS transpose -> uint4 stores.
// ---------------------------------------------------------------------------
__global__ __launch_bounds__(256) void qkv_gemm_kernel(
    const float* __restrict__ x, const ushort* __restrict__ Wt,
    const float* __restrict__ b_qkv, ushort* __restrict__ qkv)
{
    __shared__ ushort As[64 * 128];
    __shared__ ushort Bs[192 * 128];

    const int tid = threadIdx.x;
    const int m0 = blockIdx.x * 64;
    const int n0 = blockIdx.y * 192;

    // stage A: 64x128 f32 -> bf16
    #pragma unroll
    for (int t = 0; t < 4; ++t) {
        int idx = tid + t * 256;
        int r = idx >> 4, c = idx & 15;
        const float* src = x + (size_t)(m0 + r) * 128 + c * 8;
        float4 v0 = *(const float4*)src;
        float4 v1 = *(const float4*)(src + 4);
        union { ushort s[8]; uint4 q; } u;
        u.s[0] = f2bf(v0.x); u.s[1] = f2bf(v0.y); u.s[2] = f2bf(v0.z); u.s[3] = f2bf(v0.w);
        u.s[4] = f2bf(v1.x); u.s[5] = f2bf(v1.y); u.s[6] = f2bf(v1.z); u.s[7] = f2bf(v1.w);
        *(uint4*)&As[r * 128 + (c ^ (r & 7)) * 8] = u.q;
    }
    // stage B: 192x128 bf16, coalesced uint4
    #pragma unroll
    for (int t = 0; t < 12; ++t) {
        int idx = tid + t * 256;
        int r = idx >> 4, c = idx & 15;
        uint4 v = *(const uint4*)(Wt + (size_t)(n0 + r) * 128 + c * 8);
        *(uint4*)&Bs[r * 128 + (c ^ (r & 7)) * 8] = v;
    }
    __syncthreads();

    const int wid = tid >> 6, lane = tid & 63;
    const int l15 = lane & 15, l4 = lane >> 4;
    const int mr = (wid >> 1) * 32, nr = (wid & 1) * 96;

    f32x4 acc[2][6] = {};
    #pragma unroll
    for (int ks = 0; ks < 4; ++ks) {
        short8 af[2], bf[6];
        #pragma unroll
        for (int fm = 0; fm < 2; ++fm) {
            int row = mr + fm * 16 + l15;
            af[fm] = *(const short8*)&As[row * 128 + ((ks * 4 + l4) ^ (row & 7)) * 8];
        }
        #pragma unroll
        for (int fn = 0; fn < 6; ++fn) {
            int row = nr + fn * 16 + l15;
            bf[fn] = *(const short8*)&Bs[row * 128 + ((ks * 4 + l4) ^ (row & 7)) * 8];
        }
        #pragma unroll
        for (int fm = 0; fm < 2; ++fm)
            #pragma unroll
            for (int fn = 0; fn < 6; ++fn)
                acc[fm][fn] = __builtin_amdgcn_mfma_f32_16x16x32_bf16(
                    af[fm], bf[fn], acc[fm][fn], 0, 0, 0);
    }

    // epilogue: bias + scale -> bf16 into LDS (pad 200), then uint4 stores
    __syncthreads();                      // all As/Bs reads done
    ushort* C_s = Bs;                     // 64 x 200 overlay (25.6KB < 48KB)
    #pragma unroll
    for (int fn = 0; fn < 6; ++fn) {
        int colb = nr + fn * 16;
        int col = colb + l15;
        float bc = b_qkv[n0 + col];
        float sc = (n0 + colb < 128) ? SCALE : 1.0f;
        #pragma unroll
        for (int fm = 0; fm < 2; ++fm)
            #pragma unroll
            for (int reg = 0; reg < 4; ++reg) {
                int row = mr + fm * 16 + l4 * 4 + reg;
                C_s[row * 200 + col] = f2bf((acc[fm][fn][reg] + bc) * sc);
            }
    }
    __syncthreads();
    #pragma unroll
    for (int t = 0; t < 6; ++t) {
        int idx = tid + t * 256;           // 0..1535 over 64 rows x 24 chunks
        int row = idx / 24, c = idx - row * 24;
        uint4 v = *(const uint4*)&C_s[row * 200 + c * 8];
        *(uint4*)&qkv[(size_t)(m0 + row) * 384 + n0 + c * 8] = v;
    }
}

// ---------------------------------------------------------------------------
// K2: fused neighborhood attention (all 4 heads) + output projection.
// ROUND-5 PROVEN VERSION (4x8 query tile, grid 256). Unchanged.
// ---------------------------------------------------------------------------
__global__ __launch_bounds__(256) void natten_proj_kernel(
    const ushort* __restrict__ qkv,     // (B*H*W) x 384 bf16, q pre-scaled
    const float* __restrict__ rpb,      // 4 x 13 x 13
    const ushort* __restrict__ Wp_t,    // 128 x 128 bf16, [n][k]
    const float* __restrict__ b_proj,   // 128
    float* __restrict__ out)            // (B*H*W) x 128 f32
{
    __shared__ ushort K_s[NPIX * 128];
    __shared__ ushort V_s[NPIX * 128];
    __shared__ ushort AO_s[NQ * 128];
    __shared__ float attn_s[NQ * 52];
    __shared__ float rpb_s[676];

    const int tid = threadIdx.x;
    // XCD-aware swizzle (256 % 8 == 0 -> bijective)
    const int bx = ((blockIdx.x & 7) << 5) | (blockIdx.x >> 3);
    const int b  = bx >> 7;
    const int th = (bx >> 3) & 15;
    const int tw = bx & 7;
    const int h0 = th * 4, w0 = tw * 8;
    const int ho = max(0, h0 - 3), wo = max(0, w0 - 3);

    // ---- stage K/V halo: 140 pix x 16 slots (8 bf16 each) ----
    #pragma unroll
    for (int t = 0; t < 9; ++t) {
        int idx = tid + t * 256;
        if (idx < NPIX * 16) {
            int pix = idx >> 4, s = idx & 15;
            int r = pix / HALO_W, c = pix - r * HALO_W;
            int gh = min(ho + r, HH - 1), gw = min(wo + c, WW - 1);
            const ushort* gp = qkv + (size_t)((b << 12) + (gh << 6) + gw) * 384 + s * 8;
            uint4 kv = *(const uint4*)(gp + 128);
            uint4 vv = *(const uint4*)(gp + 256);
            int so = (s ^ (pix & 7)) * 8;
            *(uint4*)&K_s[pix * 128 + so] = kv;
            *(uint4*)&V_s[pix * 128 + so] = vv;
        }
    }
    #pragma unroll
    for (int t = 0; t < 3; ++t) {
        int idx = tid + t * 256;
        if (idx < 676) rpb_s[idx] = rpb[idx];
    }

    // per-thread query mapping: 32 queries x 8 lanes
    const int q = tid >> 3, t8 = tid & 7;
    const int qh = h0 + (q >> 3), qw = w0 + (q & 7);
    const int hs = min(max(qh - 3, 0), HH - 7);
    const int ws = min(max(qw - 3, 0), WW - 7);
    const int base_lp = (hs - ho) * HALO_W + (ws - wo);
    const int bh0 = hs - qh + 6, bw0 = ws - qw + 6;
    const size_t qpix = (size_t)((b << 12) + (qh << 6) + qw);

    __syncthreads();

    for (int hd = 0; hd < 4; ++hd) {
        // Q -> f32 regs
        float qf[32];
        #pragma unroll
        for (int d4 = 0; d4 < 4; ++d4) {
            uint4 qu = *(const uint4*)(qkv + qpix * 384 + hd * 32 + d4 * 8);
            qf[d4*8+0] = bflo(qu.x); qf[d4*8+1] = bfhi(qu.x);
            qf[d4*8+2] = bflo(qu.y); qf[d4*8+3] = bfhi(qu.y);
            qf[d4*8+4] = bflo(qu.z); qf[d4*8+5] = bfhi(qu.z);
            qf[d4*8+6] = bflo(qu.w); qf[d4*8+7] = bfhi(qu.w);
        }

        // QK + bias: lane t8 handles j = t8, t8+8, ...
        float lg[7];
        #pragma unroll
        for (int i = 0; i < 7; ++i) {
            int j = t8 + i * 8;
            float s = -1e30f;
            if (j < 49) {
                int p = (j * 37) >> 8;        // exact j/7 for j<=48
                int qq = j - p * 7;
                int lp = base_lp + p * HALO_W + qq;
                float a = 0.f;
                #pragma unroll
                for (int d4 = 0; d4 < 4; ++d4) {
                    uint4 ku = *(const uint4*)&K_s[lp * 128 + ((hd*4 + d4) ^ (lp & 7)) * 8];
                    a += bflo(ku.x)*qf[d4*8+0] + bfhi(ku.x)*qf[d4*8+1]
                       + bflo(ku.y)*qf[d4*8+2] + bfhi(ku.y)*qf[d4*8+3]
                       + bflo(ku.z)*qf[d4*8+4] + bfhi(ku.z)*qf[d4*8+5]
                       + bflo(ku.w)*qf[d4*8+6] + bfhi(ku.w)*qf[d4*8+7];
                }
                s = a + rpb_s[hd * 169 + (bh0 + p) * 13 + (bw0 + qq)];
            }
            lg[i] = s;
        }

        // softmax across the query's 8 lanes
        float m = lg[0];
        #pragma unroll
        for (int i = 1; i < 7; ++i) m = fmaxf(m, lg[i]);
        m = fmaxf(m, __shfl_xor(m, 1));
        m = fmaxf(m, __shfl_xor(m, 2));
        m = fmaxf(m, __shfl_xor(m, 4));
        float ssum = 0.f;
        #pragma unroll
        for (int i = 0; i < 7; ++i) {
            int j = t8 + i * 8;
            lg[i] = (j < 49) ? __expf(lg[i] - m) : 0.f;
            ssum += lg[i];
        }
        ssum += __shfl_xor(ssum, 1);
        ssum += __shfl_xor(ssum, 2);
        ssum += __shfl_xor(ssum, 4);
        float inv = 1.f / ssum;
        #pragma unroll
        for (int i = 0; i < 7; ++i) {
            int j = t8 + i * 8;
            if (j < 49) attn_s[q * 52 + j] = lg[i] * inv;   // wave-local
        }

        // PV: lane t8 accumulates dims [t8*4, t8*4+4) of head hd
        const int sv = hd * 4 + (t8 >> 1);
        const int off = (t8 & 1) * 4;
        float o0 = 0.f, o1 = 0.f, o2 = 0.f, o3 = 0.f;
        #pragma unroll
        for (int j = 0; j < 49; ++j) {
            const int p = j / 7, qq = j % 7;   // compile-time
            int lp = base_lp + p * HALO_W + qq;
            float a = attn_s[q * 52 + j];
            uint2 vu = *(const uint2*)&V_s[lp * 128 + (sv ^ (lp & 7)) * 8 + off];
            o0 += a * bflo(vu.x); o1 += a * bfhi(vu.x);
            o2 += a * bflo(vu.y); o3 += a * bfhi(vu.y);
        }
        union { ushort s[4]; uint2 u; } w;
        w.s[0] = f2bf(o0); w.s[1] = f2bf(o1); w.s[2] = f2bf(o2); w.s[3] = f2bf(o3);
        *(uint2*)&AO_s[q * 128 + (sv ^ (q & 7)) * 8 + off] = w.u;
    }
    __syncthreads();

    // ---- proj: out(32x128) = AO @ Wp^T + b_proj ----
    const int wid = tid >> 6, lane = tid & 63;
    const int l15 = lane & 15, l4 = lane >> 4;
    const int wr = wid >> 1, wc = wid & 1;

    f32x4 pacc[4] = {};
    #pragma unroll
    for (int ks = 0; ks < 4; ++ks) {
        int arow = wr * 16 + l15;
        short8 af = *(const short8*)&AO_s[arow * 128 + ((ks * 4 + l4) ^ (arow & 7)) * 8];
        #pragma unroll
        for (int fn = 0; fn < 4; ++fn) {
            int brow = wc * 64 + fn * 16 + l15;
            short8 bf = *(const short8*)(Wp_t + (size_t)brow * 128 + (ks * 4 + l4) * 8);
            pacc[fn] = __builtin_amdgcn_mfma_f32_16x16x32_bf16(af, bf, pacc[fn], 0, 0, 0);
        }
    }
    #pragma unroll
    for (int fn = 0; fn < 4; ++fn) {
        int col = wc * 64 + fn * 16 + l15;
        float bc = b_proj[col];
        #pragma unroll
        for (int reg = 0; reg < 4; ++reg) {
            int q2 = wr * 16 + l4 * 4 + reg;
            int oh = h0 + (q2 >> 3), ow = w0 + (q2 & 7);
            out[(size_t)((b << 12) + (oh << 6) + ow) * 128 + col] = pacc[fn][reg] + bc;
        }
    }
}

extern "C" void kernel_launch(void* const* d_in, const int* in_sizes, int n_in,
                              void* d_out, int out_size, void* d_ws, size_t ws_size,
                              hipStream_t stream)
{
    const float* x      = (const float*)d_in[0];
    const float* w_qkv  = (const float*)d_in[1];
    const float* b_qkv  = (const float*)d_in[2];
    const float* rpb    = (const float*)d_in[3];
    const float* w_proj = (const float*)d_in[4];
    const float* b_proj = (const float*)d_in[5];
    float* out = (float*)d_out;

    const int M = BB * HH * WW;                   // 8192
    ushort* qkv  = (ushort*)d_ws;                 // M x 384 bf16
    ushort* Wt   = qkv + (size_t)M * 384;         // 512 x 128 bf16
    ushort* Wp_t = Wt + (size_t)384 * 128;        // rows 384..511

    cvt_w_kernel<<<8, 256, 0, stream>>>(w_qkv, w_proj, Wt);

    qkv_gemm_kernel<<<dim3(128, 2), 256, 0, stream>>>(x, Wt, b_qkv, qkv);

    natten_proj_kernel<<<256, 256, 0, stream>>>(qkv, rpb, Wp_t, b_proj, out);
}

// Round 8
// 33.893 us; speedup vs baseline: 1.0029x; 1.0029x over previous
//
#include <hip/hip_runtime.h>
#include <hip/hip_bf16.h>
#include <cstddef>

#define BB 2
#define HH 64
#define WW 64
#define SCALE 0.17677669529663687f   // 32^-0.5

// natten tile geometry (round-5 proven): 4x8 queries per block, ONE head
#define HALO_H 10
#define HALO_W 14
#define NPIX 140
#define NQ 32

typedef short short8 __attribute__((ext_vector_type(8)));
typedef float f32x4 __attribute__((ext_vector_type(4)));

__device__ inline ushort f2bf(float f) {
    union { __hip_bfloat16 b; ushort u; } cv;
    cv.b = __float2bfloat16(f);
    return cv.u;
}
__device__ inline float bflo(uint u) { union { uint i; float f; } c; c.i = u << 16; return c.f; }
__device__ inline float bfhi(uint u) { union { uint i; float f; } c; c.i = u & 0xffff0000u; return c.f; }

// ---------------------------------------------------------------------------
// K0: weight transpose f32 -> bf16, LDS-tiled (round-7 proven).
// Blocks 0..5: w_qkv -> Wt rows 0..383. Blocks 6..7: w_proj -> rows 384..511.
// ---------------------------------------------------------------------------
__global__ __launch_bounds__(256) void cvt_w_kernel(
    const float* __restrict__ w_qkv, const float* __restrict__ w_proj,
    ushort* __restrict__ Wt)
{
    __shared__ float Ws[128 * 65];
    const int tid = threadIdx.x;
    const int blk = blockIdx.x;
    const float* src = (blk < 6) ? w_qkv : w_proj;
    const int srcN  = (blk < 6) ? 384 : 128;
    const int n0    = (blk < 6) ? blk * 64 : (blk - 6) * 64;
    const int obase = (blk < 6) ? n0 : 384 + n0;

    #pragma unroll
    for (int t = 0; t < 8; ++t) {
        int idx = tid + t * 256;
        int k = idx >> 4, c4 = idx & 15;
        float4 v = *(const float4*)(src + (size_t)k * srcN + n0 + c4 * 4);
        Ws[k * 65 + c4 * 4 + 0] = v.x;
        Ws[k * 65 + c4 * 4 + 1] = v.y;
        Ws[k * 65 + c4 * 4 + 2] = v.z;
        Ws[k * 65 + c4 * 4 + 3] = v.w;
    }
    __syncthreads();

    const int n = tid & 63;
    #pragma unroll
    for (int t = 0; t < 4; ++t) {
        int c = (tid >> 6) + t * 4;
        union { ushort s[8]; uint4 q; } u;
        #pragma unroll
        for (int e = 0; e < 8; ++e) u.s[e] = f2bf(Ws[(c * 8 + e) * 65 + n]);
        *(uint4*)&Wt[(size_t)(obase + n) * 128 + c * 8] = u.q;
    }
}

// ---------------------------------------------------------------------------
// K1: qkv = x @ w_qkv + b_qkv (q cols pre-scaled), bf16 out (round-7 proven).
// ---------------------------------------------------------------------------
__global__ __launch_bounds__(256) void qkv_gemm_kernel(
    const float* __restrict__ x, const ushort* __restrict__ Wt,
    const float* __restrict__ b_qkv, ushort* __restrict__ qkv)
{
    __shared__ ushort As[64 * 128];
    __shared__ ushort Bs[192 * 128];

    const int tid = threadIdx.x;
    const int m0 = blockIdx.x * 64;
    const int n0 = blockIdx.y * 192;

    #pragma unroll
    for (int t = 0; t < 4; ++t) {
        int idx = tid + t * 256;
        int r = idx >> 4, c = idx & 15;
        const float* src = x + (size_t)(m0 + r) * 128 + c * 8;
        float4 v0 = *(const float4*)src;
        float4 v1 = *(const float4*)(src + 4);
        union { ushort s[8]; uint4 q; } u;
        u.s[0] = f2bf(v0.x); u.s[1] = f2bf(v0.y); u.s[2] = f2bf(v0.z); u.s[3] = f2bf(v0.w);
        u.s[4] = f2bf(v1.x); u.s[5] = f2bf(v1.y); u.s[6] = f2bf(v1.z); u.s[7] = f2bf(v1.w);
        *(uint4*)&As[r * 128 + (c ^ (r & 7)) * 8] = u.q;
    }
    #pragma unroll
    for (int t = 0; t < 12; ++t) {
        int idx = tid + t * 256;
        int r = idx >> 4, c = idx & 15;
        uint4 v = *(const uint4*)(Wt + (size_t)(n0 + r) * 128 + c * 8);
        *(uint4*)&Bs[r * 128 + (c ^ (r & 7)) * 8] = v;
    }
    __syncthreads();

    const int wid = tid >> 6, lane = tid & 63;
    const int l15 = lane & 15, l4 = lane >> 4;
    const int mr = (wid >> 1) * 32, nr = (wid & 1) * 96;

    f32x4 acc[2][6] = {};
    #pragma unroll
    for (int ks = 0; ks < 4; ++ks) {
        short8 af[2], bf[6];
        #pragma unroll
        for (int fm = 0; fm < 2; ++fm) {
            int row = mr + fm * 16 + l15;
            af[fm] = *(const short8*)&As[row * 128 + ((ks * 4 + l4) ^ (row & 7)) * 8];
        }
        #pragma unroll
        for (int fn = 0; fn < 6; ++fn) {
            int row = nr + fn * 16 + l15;
            bf[fn] = *(const short8*)&Bs[row * 128 + ((ks * 4 + l4) ^ (row & 7)) * 8];
        }
        #pragma unroll
        for (int fm = 0; fm < 2; ++fm)
            #pragma unroll
            for (int fn = 0; fn < 6; ++fn)
                acc[fm][fn] = __builtin_amdgcn_mfma_f32_16x16x32_bf16(
                    af[fm], bf[fn], acc[fm][fn], 0, 0, 0);
    }

    __syncthreads();
    ushort* C_s = Bs;                     // 64 x 200 overlay
    #pragma unroll
    for (int fn = 0; fn < 6; ++fn) {
        int colb = nr + fn * 16;
        int col = colb + l15;
        float bc = b_qkv[n0 + col];
        float sc = (n0 + colb < 128) ? SCALE : 1.0f;
        #pragma unroll
        for (int fm = 0; fm < 2; ++fm)
            #pragma unroll
            for (int reg = 0; reg < 4; ++reg) {
                int row = mr + fm * 16 + l4 * 4 + reg;
                C_s[row * 200 + col] = f2bf((acc[fm][fn][reg] + bc) * sc);
            }
    }
    __syncthreads();
    #pragma unroll
    for (int t = 0; t < 6; ++t) {
        int idx = tid + t * 256;
        int row = idx / 24, c = idx - row * 24;
        uint4 v = *(const uint4*)&C_s[row * 200 + c * 8];
        *(uint4*)&qkv[(size_t)(m0 + row) * 384 + n0 + c * 8] = v;
    }
}

// ---------------------------------------------------------------------------
// K2: neighborhood attention, ONE head per block (round-5 inner structure,
// slot space 16->8). Block = (4x8 tile, head), grid (256, 4), ~25KB LDS ->
// 4+ blocks/CU. Writes attn_out slice bf16 directly (coalesced uint2).
// ---------------------------------------------------------------------------
__global__ __launch_bounds__(256) void natten_head_kernel(
    const ushort* __restrict__ qkv,     // (B*H*W) x 384 bf16, q pre-scaled
    const float* __restrict__ rpb,      // 4 x 13 x 13
    ushort* __restrict__ attn_out)      // (B*H*W) x 128 bf16
{
    __shared__ ushort K_s[NPIX * 32];
    __shared__ ushort V_s[NPIX * 32];
    __shared__ float attn_s[NQ * 52];
    __shared__ float rpb_s[169];

    const int hd = blockIdx.y;
    const int tid = threadIdx.x;
    // XCD-aware swizzle (256 % 8 == 0 -> bijective)
    const int bx = ((blockIdx.x & 7) << 5) | (blockIdx.x >> 3);
    const int b  = bx >> 7;
    const int th = (bx >> 3) & 15;
    const int tw = bx & 7;
    const int h0 = th * 4, w0 = tw * 8;
    const int ho = max(0, h0 - 3), wo = max(0, w0 - 3);

    // ---- stage K/V: 140 pix x 8 slots (4 K + 4 V, 8 bf16 each) ----
    #pragma unroll
    for (int t = 0; t < 5; ++t) {
        int idx = tid + t * 256;
        if (idx < NPIX * 8) {
            int pix = idx >> 3, s = idx & 7;
            int r = pix / HALO_W, c = pix - r * HALO_W;
            int gh = min(ho + r, HH - 1), gw = min(wo + c, WW - 1);
            const ushort* gp = qkv + (size_t)((b << 12) + (gh << 6) + gw) * 384
                               + 128 + (s >> 2) * 128 + hd * 32 + (s & 3) * 8;
            uint4 v = *(const uint4*)gp;
            int so = ((s & 3) ^ (pix & 3)) * 8;
            if (s < 4) *(uint4*)&K_s[pix * 32 + so] = v;
            else       *(uint4*)&V_s[pix * 32 + so] = v;
        }
    }
    if (tid < 169) rpb_s[tid] = rpb[hd * 169 + tid];

    // per-thread query mapping: 32 queries x 8 lanes
    const int q = tid >> 3, t8 = tid & 7;
    const int qh = h0 + (q >> 3), qw = w0 + (q & 7);
    const int hs = min(max(qh - 3, 0), HH - 7);
    const int ws = min(max(qw - 3, 0), WW - 7);
    const int base_lp = (hs - ho) * HALO_W + (ws - wo);
    const int bh0 = hs - qh + 6, bw0 = ws - qw + 6;
    const size_t qpix = (size_t)((b << 12) + (qh << 6) + qw);

    // Q -> f32 regs (overlaps staging)
    float qf[32];
    #pragma unroll
    for (int d4 = 0; d4 < 4; ++d4) {
        uint4 qu = *(const uint4*)(qkv + qpix * 384 + hd * 32 + d4 * 8);
        qf[d4*8+0] = bflo(qu.x); qf[d4*8+1] = bfhi(qu.x);
        qf[d4*8+2] = bflo(qu.y); qf[d4*8+3] = bfhi(qu.y);
        qf[d4*8+4] = bflo(qu.z); qf[d4*8+5] = bfhi(qu.z);
        qf[d4*8+6] = bflo(qu.w); qf[d4*8+7] = bfhi(qu.w);
    }
    __syncthreads();

    // ---- QK + bias: lane t8 handles j = t8, t8+8, ... ----
    float lg[7];
    #pragma unroll
    for (int i = 0; i < 7; ++i) {
        int j = t8 + i * 8;
        float s = -1e30f;
        if (j < 49) {
            int p = (j * 37) >> 8;            // exact j/7 for j<=48
            int qq = j - p * 7;
            int lp = base_lp + p * HALO_W + qq;
            float a = 0.f;
            #pragma unroll
            for (int d4 = 0; d4 < 4; ++d4) {
                uint4 ku = *(const uint4*)&K_s[lp * 32 + ((d4 ^ (lp & 3)) * 8)];
                a += bflo(ku.x)*qf[d4*8+0] + bfhi(ku.x)*qf[d4*8+1]
                   + bflo(ku.y)*qf[d4*8+2] + bfhi(ku.y)*qf[d4*8+3]
                   + bflo(ku.z)*qf[d4*8+4] + bfhi(ku.z)*qf[d4*8+5]
                   + bflo(ku.w)*qf[d4*8+6] + bfhi(ku.w)*qf[d4*8+7];
            }
            s = a + rpb_s[(bh0 + p) * 13 + (bw0 + qq)];
        }
        lg[i] = s;
    }

    // ---- softmax across the query's 8 lanes ----
    float m = lg[0];
    #pragma unroll
    for (int i = 1; i < 7; ++i) m = fmaxf(m, lg[i]);
    m = fmaxf(m, __shfl_xor(m, 1));
    m = fmaxf(m, __shfl_xor(m, 2));
    m = fmaxf(m, __shfl_xor(m, 4));
    float ssum = 0.f;
    #pragma unroll
    for (int i = 0; i < 7; ++i) {
        int j = t8 + i * 8;
        lg[i] = (j < 49) ? __expf(lg[i] - m) : 0.f;
        ssum += lg[i];
    }
    ssum += __shfl_xor(ssum, 1);
    ssum += __shfl_xor(ssum, 2);
    ssum += __shfl_xor(ssum, 4);
    float inv = 1.f / ssum;
    #pragma unroll
    for (int i = 0; i < 7; ++i) {
        int j = t8 + i * 8;
        if (j < 49) attn_s[q * 52 + j] = lg[i] * inv;   // wave-local relay
    }

    // ---- PV: lane t8 accumulates head-dims [t8*4, t8*4+4) ----
    const int sv = t8 >> 1;
    const int off = (t8 & 1) * 4;
    float o0 = 0.f, o1 = 0.f, o2 = 0.f, o3 = 0.f;
    #pragma unroll
    for (int j = 0; j < 49; ++j) {
        const int p = j / 7, qq = j % 7;      // compile-time
        int lp = base_lp + p * HALO_W + qq;
        float a = attn_s[q * 52 + j];
        uint2 vu = *(const uint2*)&V_s[lp * 32 + ((sv ^ (lp & 3)) * 8) + off];
        o0 += a * bflo(vu.x); o1 += a * bfhi(vu.x);
        o2 += a * bflo(vu.y); o3 += a * bfhi(vu.y);
    }
    union { ushort s[4]; uint2 u; } w;
    w.s[0] = f2bf(o0); w.s[1] = f2bf(o1); w.s[2] = f2bf(o2); w.s[3] = f2bf(o3);
    *(uint2*)(attn_out + qpix * 128 + hd * 32 + t8 * 4) = w.u;
}

// ---------------------------------------------------------------------------
// K3: out = attn_out @ w_proj^T + b_proj (round-4 proven structure).
// BM=32 x BN=128, K=128 staged, 4 waves 2x2, f32 out.
// ---------------------------------------------------------------------------
__global__ __launch_bounds__(256) void proj_gemm_kernel(
    const ushort* __restrict__ A,      // M x 128 bf16
    const ushort* __restrict__ Bt,     // [128][128] bf16, n-major
    const float* __restrict__ bias,    // 128
    float* __restrict__ C)             // M x 128 f32
{
    __shared__ ushort As[32 * 128];
    __shared__ ushort Bs[128 * 128];

    const int m0 = blockIdx.x * 32;
    const int tid = threadIdx.x;

    #pragma unroll
    for (int L = tid; L < 32 * 16; L += 256) {
        int r = L >> 4, c = L & 15;
        uint4 v = *(const uint4*)(A + (size_t)(m0 + r) * 128 + c * 8);
        *(uint4*)&As[r * 128 + (c ^ (r & 7)) * 8] = v;
    }
    #pragma unroll
    for (int L = tid; L < 128 * 16; L += 256) {
        int r = L >> 4, c = L & 15;
        uint4 v = *(const uint4*)(Bt + (size_t)r * 128 + c * 8);
        *(uint4*)&Bs[r * 128 + (c ^ (r & 7)) * 8] = v;
    }
    __syncthreads();

    const int wid = tid >> 6, lane = tid & 63;
    const int wr = wid >> 1, wc = wid & 1;
    const int mr = wr * 16, nr = wc * 64;
    const int l15 = lane & 15, l4 = lane >> 4;

    f32x4 acc[4] = {};
    #pragma unroll
    for (int ks = 0; ks < 4; ++ks) {
        int arow = mr + l15;
        short8 af = *(const short8*)&As[arow * 128 + ((ks * 4 + l4) ^ (arow & 7)) * 8];
        #pragma unroll
        for (int fn = 0; fn < 4; ++fn) {
            int brow = nr + fn * 16 + l15;
            short8 bf = *(const short8*)&Bs[brow * 128 + ((ks * 4 + l4) ^ (brow & 7)) * 8];
            acc[fn] = __builtin_amdgcn_mfma_f32_16x16x32_bf16(af, bf, acc[fn], 0, 0, 0);
        }
    }

    #pragma unroll
    for (int fn = 0; fn < 4; ++fn) {
        int col = nr + fn * 16 + l15;
        float bc = bias[col];
        #pragma unroll
        for (int reg = 0; reg < 4; ++reg) {
            int row = m0 + mr + l4 * 4 + reg;
            C[(size_t)row * 128 + col] = acc[fn][reg] + bc;
        }
    }
}

extern "C" void kernel_launch(void* const* d_in, const int* in_sizes, int n_in,
                              void* d_out, int out_size, void* d_ws, size_t ws_size,
                              hipStream_t stream)
{
    const float* x      = (const float*)d_in[0];
    const float* w_qkv  = (const float*)d_in[1];
    const float* b_qkv  = (const float*)d_in[2];
    const float* rpb    = (const float*)d_in[3];
    const float* w_proj = (const float*)d_in[4];
    const float* b_proj = (const float*)d_in[5];
    float* out = (float*)d_out;

    const int M = BB * HH * WW;                   // 8192
    ushort* qkv     = (ushort*)d_ws;              // M x 384 bf16
    ushort* attn_bf = qkv + (size_t)M * 384;      // M x 128 bf16
    ushort* Wt      = attn_bf + (size_t)M * 128;  // 512 x 128 bf16
    ushort* Wt_proj = Wt + (size_t)384 * 128;     // rows 384..511

    cvt_w_kernel<<<8, 256, 0, stream>>>(w_qkv, w_proj, Wt);

    qkv_gemm_kernel<<<dim3(128, 2), 256, 0, stream>>>(x, Wt, b_qkv, qkv);

    natten_head_kernel<<<dim3(256, 4), 256, 0, stream>>>(qkv, rpb, attn_bf);

    proj_gemm_kernel<<<256, 256, 0, stream>>>(attn_bf, Wt_proj, b_proj, out);
}